// Round 3
// baseline (179.262 us; speedup 1.0000x reference)
//
#include <hip/hip_runtime.h>
#include <cstdint>
#include <math.h>

#define N_     8192
#define D_     256
#define NLBL   128
#define TEMP_INV 14.285714285714286f
#define HARDK  10
#define THETA  0.16f
#define CAP    128              // per-row collect capacity (mean ~43)
#define GCAP   256              // per-label list capacity (mean 64)

#define RB     128              // rows per block (4 waves x 32)
#define NCHUNK 8
#define CHUNK  (N_ / NCHUNK)    // 1024 cols per block
#define TILES  (CHUNK / 32)     // 32

typedef __attribute__((ext_vector_type(8)))  short bf16x8;
typedef __attribute__((ext_vector_type(16))) float f32x16;

// ---------------- Threefry-2x32, key=(0,42): exact-match validated in R1/R2 ----------------
__device__ __forceinline__ uint32_t rotl32(uint32_t x, int n) {
  return (x << n) | (x >> (32 - n));
}
__device__ uint32_t tf_bits(uint32_t idx) {
  uint32_t x0 = 0u, x1 = idx;
  const uint32_t k0 = 0u, k1 = 42u;
  const uint32_t k2 = k0 ^ k1 ^ 0x1BD11BDAu;
  x0 += k0; x1 += k1;
#define TFR(r) { x0 += x1; x1 = rotl32(x1, r); x1 ^= x0; }
  TFR(13) TFR(15) TFR(26) TFR(6)
  x0 += k1; x1 += k2 + 1u;
  TFR(17) TFR(29) TFR(16) TFR(24)
  x0 += k2; x1 += k0 + 2u;
  TFR(13) TFR(15) TFR(26) TFR(6)
  x0 += k0; x1 += k1 + 3u;
  TFR(17) TFR(29) TFR(16) TFR(24)
  x0 += k1; x1 += k2 + 4u;
  TFR(13) TFR(15) TFR(26) TFR(6)
  x0 += k2; x1 += k0 + 5u;
#undef TFR
  return x0 ^ x1;
}

__device__ __forceinline__ unsigned short f2bf(float x) {  // RNE
  uint32_t b = __float_as_uint(x);
  return (unsigned short)((b + 0x7FFFu + ((b >> 16) & 1u)) >> 16);
}

// ---------------- K1: inv_norm + bf16 z (4 rows/block) ----------------
__global__ __launch_bounds__(256) void prep_kernel(const float* __restrict__ feats,
                                                   float* __restrict__ inv_norm,
                                                   unsigned short* __restrict__ zbf) {
  const int i = blockIdx.x * 4 + (threadIdx.x >> 6);
  const int l = threadIdx.x & 63;
  float4 v = ((const float4*)feats)[(size_t)i * 64 + l];
  float ss = v.x * v.x + v.y * v.y + v.z * v.z + v.w * v.w;
#pragma unroll
  for (int o = 32; o; o >>= 1) ss += __shfl_xor(ss, o);
  float inv = 1.0f / fmaxf(sqrtf(ss), 1e-12f);
  if (l == 0) inv_norm[i] = inv;
  uint2 p;
  p.x = (uint32_t)f2bf(v.x * inv) | ((uint32_t)f2bf(v.y * inv) << 16);
  p.y = (uint32_t)f2bf(v.z * inv) | ((uint32_t)f2bf(v.w * inv) << 16);
  ((uint2*)zbf)[(size_t)i * 64 + l] = p;
}

// ---------------- K2: per-label member list + zero collect counters ----------------
__global__ __launch_bounds__(256) void group_kernel(const int* __restrict__ labels,
                                                    int* __restrict__ glist,
                                                    int* __restrict__ cnt_g,
                                                    int* __restrict__ cnt) {
  const int b = blockIdx.x;
  const int tid = threadIdx.x;
  __shared__ int lcnt;
  {
    int g = b * 256 + tid;
    if (g < N_) cnt[g] = 0;
  }
  if (tid == 0) lcnt = 0;
  __syncthreads();
  for (int it = tid; it < N_; it += 256) {
    if (labels[it] == b) {
      int p = atomicAdd(&lcnt, 1);
      if (p < GCAP) glist[b * GCAP + p] = it;
    }
  }
  __syncthreads();
  if (tid == 0) cnt_g[b] = lcnt;
}

// ---------------- K3: MFMA sim + threshold collect ----------------
__device__ __forceinline__ void stage_tile(const unsigned short* zbf, char (*AbK)[1024],
                                           int colT, int wid, int l, int kg) {
  const char* base = (const char*)zbf + ((size_t)(colT + (l & 31)) * (D_ * 2) + kg * 16);
#pragma unroll
  for (int q = 0; q < 4; ++q) {
    const int kk = wid * 4 + q;
    __builtin_amdgcn_global_load_lds(
        (const __attribute__((address_space(1))) void*)(base + kk * 32),
        (__attribute__((address_space(3))) void*)(&AbK[kk][0]), 16, 0, 0);
  }
}

__global__ __launch_bounds__(256) void collect_kernel(const unsigned short* __restrict__ zbf,
                                                      float* __restrict__ vals,
                                                      int* __restrict__ cand,
                                                      int* __restrict__ cnt) {
  __shared__ char Ab[2][16][1024];  // [buf][kk][lane*16]

  const int tid = threadIdx.x;
  const int l = tid & 63, wid = tid >> 6;
  const int kg = l >> 5;
  const int bx = blockIdx.x;
  const int rc = bx & 63, cc = bx >> 6;
  const int row0 = rc * RB;
  const int col0 = cc * CHUNK;
  const int rowW = row0 + wid * 32 + (l & 31);

  // B fragments: 16 K-steps of this lane's row (64 VGPRs)
  bf16x8 bfrag[16];
  {
    const bf16x8* zr = (const bf16x8*)(zbf + (size_t)rowW * D_);
#pragma unroll
    for (int kk = 0; kk < 16; ++kk) bfrag[kk] = zr[kk * 2 + kg];
  }

  stage_tile(zbf, Ab[0], col0, wid, l, kg);
  __syncthreads();

  int buf = 0;
  int jbase = col0 + 4 * kg;
  for (int t = 0; t < TILES; ++t) {
    if (t + 1 < TILES) stage_tile(zbf, Ab[buf ^ 1], col0 + (t + 1) * 32, wid, l, kg);

    f32x16 acc;
#pragma unroll
    for (int r = 0; r < 16; ++r) acc[r] = 0.f;
#pragma unroll
    for (int kk = 0; kk < 16; ++kk) {
      bf16x8 a = *(const bf16x8*)&Ab[buf][kk][l * 16];
      acc = __builtin_amdgcn_mfma_f32_32x32x16_bf16(a, bfrag[kk], acc, 0, 0, 0);
    }

    // lane owns row i = rowW; acc[r] = sim(i, jbase + cpos(r)), cpos = (r&3)+8*(r>>2)
#pragma unroll
    for (int r = 0; r < 16; ++r) {
      const int cpos = (r & 3) + 8 * (r >> 2);
      float c = acc[r];
      if (__any(c > THETA)) {
        if (c > THETA) {
          int pos = atomicAdd(&cnt[rowW], 1);
          if (pos < CAP) {
            cand[rowW * CAP + pos] = jbase + cpos;
            vals[rowW * CAP + pos] = c;
          }
        }
      }
    }
    __syncthreads();
    buf ^= 1;
    jbase += 32;
  }
}

// ---------------- K4: finalize (1 wave/row): pos pick + top-10 of collected + loss ----------------
__global__ __launch_bounds__(256) void finalize_kernel(
    const float* __restrict__ feats, const int* __restrict__ labels,
    const float* __restrict__ inv_norm,
    const int* __restrict__ glist, const int* __restrict__ cnt_g,
    const int* __restrict__ cnt, const int* __restrict__ cand,
    const float* __restrict__ vals,
    float* __restrict__ li, int* __restrict__ valid) {
  const int row = blockIdx.x * 4 + (threadIdx.x >> 6);
  const int lane = threadIdx.x & 63;
  const int lab = labels[row];
  const int gc = cnt_g[lab];
  const int gn = gc < GCAP ? gc : GCAP;
  const float4* feats4 = (const float4*)feats;

  // --- positive pick: threefry argmax over same-label (excl self) ---
  uint32_t bk = 0u; int bj = -1;
  for (int e = lane; e < gn; e += 64) {
    int j = glist[lab * GCAP + e];
    if (j != row) {
      uint32_t key = tf_bits((uint32_t)row * (uint32_t)N_ + (uint32_t)j) >> 9;
      if (bj < 0 || key > bk || (key == bk && j < bj)) { bk = key; bj = j; }
    }
  }
#pragma unroll
  for (int o = 32; o; o >>= 1) {
    uint32_t ok = __shfl_xor(bk, o);
    int oj = __shfl_xor(bj, o);
    if (oj >= 0 && (bj < 0 || ok > bk || (ok == bk && oj < bj))) { bk = ok; bj = oj; }
  }

  // --- exact fp32 positive cosine ---
  float pc = 0.f;
  if (bj >= 0) {
    float4 a = feats4[(size_t)row * 64 + lane];
    float4 b = feats4[(size_t)bj * 64 + lane];
    float p = a.x * b.x + a.y * b.y + a.z * b.z + a.w * b.w;
#pragma unroll
    for (int o = 32; o; o >>= 1) p += __shfl_xor(p, o);
    pc = p * inv_norm[row] * inv_norm[bj];
  }

  // --- load collected candidates (2 slots/lane), filter self/same-label ---
  const int m = cnt[row];
  const int n = m < CAP ? m : CAP;
  float v0 = -INFINITY, v1 = -INFINITY;
  if (lane < n) {
    int j = cand[row * CAP + lane];
    if (j != row && labels[j] != lab) v0 = vals[row * CAP + lane];
  }
  if (lane + 64 < n) {
    int j = cand[row * CAP + lane + 64];
    if (j != row && labels[j] != lab) v1 = vals[row * CAP + lane + 64];
  }

  float num = expf(pc * TEMP_INV);
  float den = num;
  int got = 0;
#pragma unroll 1
  for (int it = 0; it < HARDK; ++it) {
    float lm = fmaxf(v0, v1);
    float wm = lm;
#pragma unroll
    for (int o = 32; o; o >>= 1) wm = fmaxf(wm, __shfl_xor(wm, o));
    if (wm < -1e37f) break;
    den += expf(wm * TEMP_INV);
    ++got;
    unsigned long long b = __ballot(lm == wm);
    int fl = __ffsll((long long)b) - 1;
    if (lane == fl) { if (v0 == wm) v0 = -INFINITY; else v1 = -INFINITY; }
  }

  const int ndiff = N_ - gc;
  const bool vld = (bj >= 0) && (ndiff > 0);
  const int want = ndiff < HARDK ? ndiff : HARDK;

  // --- exact fallback (statistically never taken; guarantees correctness) ---
  if (vld && (m > CAP || got < want)) {
    float t[HARDK];
#pragma unroll
    for (int k = 0; k < HARDK; ++k) t[k] = -INFINITY;
    const float invr = inv_norm[row];
    for (int j = lane; j < N_; j += 64) {
      if (j == row || labels[j] == lab) continue;
      const float4* fr = feats4 + (size_t)row * 64;
      const float4* fj = feats4 + (size_t)j * 64;
      float p = 0.f;
      for (int d = 0; d < 64; ++d) {
        float4 x = fr[d], y = fj[d];
        p += x.x * y.x + x.y * y.y + x.z * y.z + x.w * y.w;
      }
      float c = p * invr * inv_norm[j];
#pragma unroll
      for (int q = 0; q < HARDK; ++q) {
        float hi = fmaxf(t[q], c);
        c = fminf(t[q], c);
        t[q] = hi;
      }
    }
    den = num;
#pragma unroll 1
    for (int it = 0; it < HARDK; ++it) {
      float lm = t[0];
      float wm = lm;
#pragma unroll
      for (int o = 32; o; o >>= 1) wm = fmaxf(wm, __shfl_xor(wm, o));
      if (wm < -1e37f) break;
      den += expf(wm * TEMP_INV);
      unsigned long long b = __ballot(lm == wm);
      int fl = __ffsll((long long)b) - 1;
      if (lane == fl) {
#pragma unroll
        for (int q = 0; q < HARDK - 1; ++q) t[q] = t[q + 1];
        t[HARDK - 1] = -INFINITY;
      }
    }
  }

  float L = 0.f;
  if (vld) L = -logf(fmaxf(num / fmaxf(den, 1e-8f), 1e-8f));
  if (lane == 0) {
    li[row] = L;
    valid[row] = vld ? 1 : 0;
  }
}

// ---------------- K5: final mean ----------------
__global__ __launch_bounds__(256) void reduce_kernel(const float* __restrict__ li,
                                                     const int* __restrict__ valid,
                                                     float* __restrict__ out) {
  __shared__ float ssum[4];
  __shared__ int scnt[4];
  float s = 0.f; int c = 0;
  for (int i = threadIdx.x; i < N_; i += 256) { s += li[i]; c += valid[i]; }
#pragma unroll
  for (int o = 32; o; o >>= 1) { s += __shfl_down(s, o); c += __shfl_down(c, o); }
  if ((threadIdx.x & 63) == 0) { ssum[threadIdx.x >> 6] = s; scnt[threadIdx.x >> 6] = c; }
  __syncthreads();
  if (threadIdx.x == 0) {
    float S = 0.f; int C = 0;
    for (int w = 0; w < 4; ++w) { S += ssum[w]; C += scnt[w]; }
    out[0] = S / (float)(C > 0 ? C : 1);
  }
}

extern "C" void kernel_launch(void* const* d_in, const int* in_sizes, int n_in,
                              void* d_out, int out_size, void* d_ws, size_t ws_size,
                              hipStream_t stream) {
  const float* feats  = (const float*)d_in[0];
  const int*   labels = (const int*)d_in[1];
  float* out = (float*)d_out;

  char* w = (char*)d_ws;
  unsigned short* zbf = (unsigned short*)w;  w += (size_t)N_ * D_ * 2;       // 4 MB
  float* inv_norm = (float*)w;               w += (size_t)N_ * 4;
  int* glist = (int*)w;                      w += (size_t)NLBL * GCAP * 4;   // 128 KB
  int* cnt_g = (int*)w;                      w += (size_t)NLBL * 4;
  int* cnt = (int*)w;                        w += (size_t)N_ * 4;
  int* cand = (int*)w;                       w += (size_t)N_ * CAP * 4;      // 4 MB
  float* vals = (float*)w;                   w += (size_t)N_ * CAP * 4;      // 4 MB
  float* li_arr = (float*)w;                 w += (size_t)N_ * 4;
  int* valid_arr = (int*)w;                  w += (size_t)N_ * 4;

  hipLaunchKernelGGL(prep_kernel, dim3(N_ / 4), dim3(256), 0, stream, feats, inv_norm, zbf);
  hipLaunchKernelGGL(group_kernel, dim3(NLBL), dim3(256), 0, stream, labels, glist, cnt_g, cnt);
  hipLaunchKernelGGL(collect_kernel, dim3(64 * NCHUNK), dim3(256), 0, stream, zbf, vals, cand, cnt);
  hipLaunchKernelGGL(finalize_kernel, dim3(N_ / 4), dim3(256), 0, stream,
                     feats, labels, inv_norm, glist, cnt_g, cnt, cand, vals, li_arr, valid_arr);
  hipLaunchKernelGGL(reduce_kernel, dim3(1), dim3(256), 0, stream, li_arr, valid_arr, out);
}